// Round 1
// baseline (1296.143 us; speedup 1.0000x reference)
//
#include <hip/hip_runtime.h>
#include <math.h>

// EdgeSelector: B=32, N=64, D=64, H=4, E=256, HD=64
// out = [em (32,64,4,64) | sampled (32,64,4,64)] f32, out_size = 1048576
//
// ws layout (floats): xn[2048*64] | T1[2048*768] | T2[2048*768]  (~13.1 MB)

#define SA 132   // LDS row stride for 128-wide tiles (An, Wc)
#define SQ 68    // LDS row stride for 64-wide tiles (q,k,vT,w,A2,w1)

#define OFF_AN   0                    // [64][132]  An (later aliased: w1 [64][68])
#define OFF_WCS  (64 * 132)           // [64][132]  Wc slice (later aliased: w [64][68])
#define OFF_Q    (OFF_WCS + 64 * 132) // [64][68]   q (later aliased: A2)
#define OFF_K    (OFF_Q + 64 * 68)    // [64][68]
#define OFF_VT   (OFF_K + 64 * 68)    // [64][68]   v transposed: vT[d][k]
#define OFF_SM   (OFF_VT + 64 * 68)
#define OFF_T2H  (OFF_SM)             // 192: T2 slice for this head, [part][64]
#define OFF_MASKR (OFF_SM + 192)      // 64: mask[b,t,:]
#define OFF_LOG  (OFF_SM + 256)       // 64: logits
#define OFF_B1   (OFF_SM + 320)       // 64
#define OFF_W2   (OFF_SM + 384)       // 64
#define LDS_TOT  (OFF_SM + 448)       // 30400 floats = 121,600 B

// ---------------- K1: xn = LN(x)*g+b, zeroed where row has no neighbors ----
__global__ __launch_bounds__(256) void k_node_ln(
    const float* __restrict__ x, const int* __restrict__ mask,
    const float* __restrict__ g, const float* __restrict__ bb,
    float* __restrict__ xn) {
  int tid = threadIdx.x;
  int row = blockIdx.x * 4 + (tid >> 6);  // b*64 + i, 2048 rows
  int lane = tid & 63;
  float v = x[row * 64 + lane];
  float s = v;
#pragma unroll
  for (int m = 1; m < 64; m <<= 1) s += __shfl_xor(s, m, 64);
  float mean = s * (1.0f / 64.0f);
  float dv = v - mean;
  float s2 = dv * dv;
#pragma unroll
  for (int m = 1; m < 64; m <<= 1) s2 += __shfl_xor(s2, m, 64);
  float rstd = rsqrtf(s2 * (1.0f / 64.0f) + 1e-5f);
  float msum = (float)mask[row * 64 + lane];
#pragma unroll
  for (int m = 1; m < 64; m <<= 1) msum += __shfl_xor(msum, m, 64);
  float ped = (msum > 0.0f) ? 1.0f : 0.0f;
  xn[row * 64 + lane] = (dv * rstd * g[lane] + bb[lane]) * ped;
}

// ---------------- K2: T1[r,f]=W[f,0:64]·xn[r]; T2[r,f]=W[f,64:128]·xn[r]+bias[f]
__global__ __launch_bounds__(256) void k_t12(
    const float* __restrict__ xn, const float* __restrict__ W,
    const float* __restrict__ bias, float* __restrict__ T1, float* __restrict__ T2) {
  __shared__ __align__(16) float sx[8 * 64];
  int tid = threadIdx.x;
  int r0 = blockIdx.x * 8;
#pragma unroll
  for (int u = 0; u < 2; ++u) {
    int idx = tid + 256 * u;
    sx[idx] = xn[r0 * 64 + idx];
  }
  __syncthreads();
#pragma unroll
  for (int ff = 0; ff < 3; ++ff) {
    int f = tid + 256 * ff;
    float acc1[8], acc2[8];
#pragma unroll
    for (int r = 0; r < 8; ++r) { acc1[r] = 0.f; acc2[r] = 0.f; }
    for (int e4 = 0; e4 < 64; e4 += 4) {
      float4 wa = *(const float4*)&W[f * 256 + e4];
      float4 wb = *(const float4*)&W[f * 256 + 64 + e4];
#pragma unroll
      for (int r = 0; r < 8; ++r) {
        float4 xv = *(const float4*)&sx[r * 64 + e4];
        acc1[r] += wa.x * xv.x + wa.y * xv.y + wa.z * xv.z + wa.w * xv.w;
        acc2[r] += wb.x * xv.x + wb.y * xv.y + wb.z * xv.z + wb.w * xv.w;
      }
    }
    float bv = bias[f];
#pragma unroll
    for (int r = 0; r < 8; ++r) {
      T1[(r0 + r) * 768 + f] = acc1[r];
      T2[(r0 + r) * 768 + f] = acc2[r] + bv;
    }
  }
}

// ---------------- K3: fused per-(b,t,h) projection + attention + MLP + softmaxes
__global__ __launch_bounds__(256) void k_main(
    const float* __restrict__ A, const int* __restrict__ mask,
    const float* __restrict__ gu, const float* __restrict__ leg,
    const float* __restrict__ leb, const float* __restrict__ W,
    const float* __restrict__ w1, const float* __restrict__ b1,
    const float* __restrict__ w2, const float* __restrict__ b2,
    const float* __restrict__ T1, const float* __restrict__ T2,
    float* __restrict__ out) {
  __shared__ __align__(16) float lds[LDS_TOT];
  int tid = threadIdx.x;
  int bid = blockIdx.x;
  int h = bid & 3;
  int t = (bid >> 2) & 63;
  int b = bid >> 8;
  int bt = b * 64 + t;

  // ---- stage small constants ----
  if (tid < 192)
    lds[OFF_T2H + tid] = T2[bt * 768 + (tid >> 6) * 256 + h * 64 + (tid & 63)];
  else  // tid 192..255 -> mask row
    lds[OFF_MASKR + (tid - 192)] = (float)mask[bt * 64 + (tid - 192)];
  if (tid < 64) lds[OFF_B1 + tid] = b1[tid];
  else if (tid < 128) lds[OFF_W2 + (tid - 64)] = w2[tid - 64];

  // ---- stage An = (LN(A[b,m,t,:]))*mask[b,t,m], rows m=0..63, e=0..127 ----
  {
    int wave = tid >> 6, lane = tid & 63, half = lane >> 5, l5 = lane & 31;
#pragma unroll
    for (int it = 0; it < 8; ++it) {
      int m = it * 8 + wave * 2 + half;
      const float* Ar = A + ((size_t)((b * 64 + m) * 64 + t)) * 128;
      float4 a = *(const float4*)&Ar[l5 * 4];
      float s = a.x + a.y + a.z + a.w;
      float s2 = a.x * a.x + a.y * a.y + a.z * a.z + a.w * a.w;
#pragma unroll
      for (int mm = 1; mm < 32; mm <<= 1) {
        s += __shfl_xor(s, mm, 32);
        s2 += __shfl_xor(s2, mm, 32);
      }
      float mean = s * (1.0f / 128.0f);
      float var = s2 * (1.0f / 128.0f) - mean * mean;
      float rstd = rsqrtf(var + 1e-5f);
      float mv = (float)mask[bt * 64 + m];
      float4 g4 = *(const float4*)&leg[l5 * 4];
      float4 b4 = *(const float4*)&leb[l5 * 4];
      float4 an;
      an.x = ((a.x - mean) * rstd * g4.x + b4.x) * mv;
      an.y = ((a.y - mean) * rstd * g4.y + b4.y) * mv;
      an.z = ((a.z - mean) * rstd * g4.z + b4.z) * mv;
      an.w = ((a.w - mean) * rstd * g4.w + b4.w) * mv;
      *(float4*)&lds[OFF_AN + m * SA + l5 * 4] = an;
    }
  }

  // ---- projection: parts p=0(q),1(k),2(v); qkv[m,d] = An[m]·Wc[f] + T1 + T2h
  for (int p = 0; p < 3; ++p) {
    __syncthreads();
    int Fbase = p * 256 + h * 64;
#pragma unroll
    for (int u = 0; u < 8; ++u) {
      int idx = tid + 256 * u;           // 2048 float4s = 64 rows x 32
      int dR = idx >> 5, c = idx & 31;
      float4 wv = *(const float4*)&W[(size_t)(Fbase + dR) * 256 + 128 + c * 4];
      *(float4*)&lds[OFF_WCS + dR * SA + c * 4] = wv;
    }
    __syncthreads();
    int md = tid >> 4, dd = tid & 15;
    float acc[4][4];
#pragma unroll
    for (int i = 0; i < 4; ++i)
#pragma unroll
      for (int j = 0; j < 4; ++j) acc[i][j] = 0.f;
    for (int e4 = 0; e4 < 128; e4 += 4) {
      float4 Af[4], Bf[4];
#pragma unroll
      for (int i = 0; i < 4; ++i)
        Af[i] = *(const float4*)&lds[OFF_AN + (md + 16 * i) * SA + e4];
#pragma unroll
      for (int j = 0; j < 4; ++j)
        Bf[j] = *(const float4*)&lds[OFF_WCS + (dd + 16 * j) * SA + e4];
#pragma unroll
      for (int i = 0; i < 4; ++i)
#pragma unroll
        for (int j = 0; j < 4; ++j)
          acc[i][j] += Af[i].x * Bf[j].x + Af[i].y * Bf[j].y +
                       Af[i].z * Bf[j].z + Af[i].w * Bf[j].w;
    }
#pragma unroll
    for (int i = 0; i < 4; ++i) {
      int m = md + 16 * i;
#pragma unroll
      for (int j = 0; j < 4; ++j) {
        int dcol = dd + 16 * j;
        float val = acc[i][j] + T1[(size_t)(b * 64 + m) * 768 + Fbase + dcol] +
                    lds[OFF_T2H + p * 64 + dcol];
        if (p == 0) lds[OFF_Q + m * SQ + dcol] = val * 0.125f;  // * hd^-0.5
        else if (p == 1) lds[OFF_K + m * SQ + dcol] = val;
        else lds[OFF_VT + dcol * SQ + m] = val;                 // transposed
      }
    }
  }
  __syncthreads();

  // ---- stage w1 into the (dead) An region ----
#pragma unroll
  for (int u = 0; u < 4; ++u) {
    int idx = tid + 256 * u;  // 1024 float4s = 64 rows x 16
    int o = idx >> 4, c = idx & 15;
    float4 wv = *(const float4*)&w1[o * 64 + c * 4];
    *(float4*)&lds[OFF_AN + o * SQ + c * 4] = wv;
  }

  // ---- scores[j,k] = q[j]·k[k]; softmax over k; *m3; renorm -> w in WCS region
  {
    int jd = tid >> 4, kd = tid & 15;
    float sc[4][4];
#pragma unroll
    for (int i = 0; i < 4; ++i)
#pragma unroll
      for (int j = 0; j < 4; ++j) sc[i][j] = 0.f;
    for (int d4 = 0; d4 < 64; d4 += 4) {
      float4 qf[4], kf[4];
#pragma unroll
      for (int i = 0; i < 4; ++i)
        qf[i] = *(const float4*)&lds[OFF_Q + (jd + 16 * i) * SQ + d4];
#pragma unroll
      for (int j = 0; j < 4; ++j)
        kf[j] = *(const float4*)&lds[OFF_K + (kd + 16 * j) * SQ + d4];
#pragma unroll
      for (int i = 0; i < 4; ++i)
#pragma unroll
        for (int j = 0; j < 4; ++j)
          sc[i][j] += qf[i].x * kf[j].x + qf[i].y * kf[j].y +
                      qf[i].z * kf[j].z + qf[i].w * kf[j].w;
    }
    float mj[4], mk[4];
#pragma unroll
    for (int i = 0; i < 4; ++i) mj[i] = lds[OFF_MASKR + jd + 16 * i];
#pragma unroll
    for (int j = 0; j < 4; ++j) mk[j] = lds[OFF_MASKR + kd + 16 * j];
#pragma unroll
    for (int i = 0; i < 4; ++i) {
      float mx = fmaxf(fmaxf(sc[i][0], sc[i][1]), fmaxf(sc[i][2], sc[i][3]));
#pragma unroll
      for (int mm = 1; mm < 16; mm <<= 1) mx = fmaxf(mx, __shfl_xor(mx, mm, 16));
      float pj[4], Z = 0.f;
#pragma unroll
      for (int j = 0; j < 4; ++j) { pj[j] = expf(sc[i][j] - mx); Z += pj[j]; }
#pragma unroll
      for (int mm = 1; mm < 16; mm <<= 1) Z += __shfl_xor(Z, mm, 16);
      float wp[4], S = 0.f;
      float invZ = 1.0f / Z;
#pragma unroll
      for (int j = 0; j < 4; ++j) { wp[j] = pj[j] * invZ * mj[i] * mk[j]; S += wp[j]; }
#pragma unroll
      for (int mm = 1; mm < 16; mm <<= 1) S += __shfl_xor(S, mm, 16);
      float inv = 1.0f / (S + 1e-10f);
#pragma unroll
      for (int j = 0; j < 4; ++j)
        lds[OFF_WCS + (jd + 16 * i) * SQ + (kd + 16 * j)] = wp[j] * inv;
    }
  }
  __syncthreads();

  // ---- A2[j,d] = sum_k w[j,k]*v[k,d]  (reads w + vT, writes into Q region)
  {
    int jd = tid >> 4, dd = tid & 15;
    float a2[4][4];
#pragma unroll
    for (int i = 0; i < 4; ++i)
#pragma unroll
      for (int j = 0; j < 4; ++j) a2[i][j] = 0.f;
    for (int k4 = 0; k4 < 64; k4 += 4) {
      float4 wf[4], vf[4];
#pragma unroll
      for (int i = 0; i < 4; ++i)
        wf[i] = *(const float4*)&lds[OFF_WCS + (jd + 16 * i) * SQ + k4];
#pragma unroll
      for (int j = 0; j < 4; ++j)
        vf[j] = *(const float4*)&lds[OFF_VT + (dd + 16 * j) * SQ + k4];
#pragma unroll
      for (int i = 0; i < 4; ++i)
#pragma unroll
        for (int j = 0; j < 4; ++j)
          a2[i][j] += wf[i].x * vf[j].x + wf[i].y * vf[j].y +
                      wf[i].z * vf[j].z + wf[i].w * vf[j].w;
    }
#pragma unroll
    for (int i = 0; i < 4; ++i)
#pragma unroll
      for (int j = 0; j < 4; ++j)
        lds[OFF_Q + (jd + 16 * i) * SQ + (dd + 16 * j)] = a2[i][j];
  }
  __syncthreads();

  // ---- hmid[j,o] = relu(A2[j]·w1[o] + b1[o]); logits[j] = hmid[j]·w2 ----
  {
    int jd = tid >> 4, od = tid & 15;
    float hm[4][4];
#pragma unroll
    for (int i = 0; i < 4; ++i)
#pragma unroll
      for (int j = 0; j < 4; ++j) hm[i][j] = 0.f;
    for (int d4 = 0; d4 < 64; d4 += 4) {
      float4 af[4], wf[4];
#pragma unroll
      for (int i = 0; i < 4; ++i)
        af[i] = *(const float4*)&lds[OFF_Q + (jd + 16 * i) * SQ + d4];
#pragma unroll
      for (int j = 0; j < 4; ++j)
        wf[j] = *(const float4*)&lds[OFF_AN + (od + 16 * j) * SQ + d4];
#pragma unroll
      for (int i = 0; i < 4; ++i)
#pragma unroll
        for (int j = 0; j < 4; ++j)
          hm[i][j] += af[i].x * wf[j].x + af[i].y * wf[j].y +
                      af[i].z * wf[j].z + af[i].w * wf[j].w;
    }
#pragma unroll
    for (int i = 0; i < 4; ++i) {
      float pp = 0.f;
#pragma unroll
      for (int j = 0; j < 4; ++j) {
        float hv = fmaxf(hm[i][j] + lds[OFF_B1 + od + 16 * j], 0.f);
        pp += hv * lds[OFF_W2 + od + 16 * j];
      }
#pragma unroll
      for (int mm = 1; mm < 16; mm <<= 1) pp += __shfl_xor(pp, mm, 16);
      if (od == 0) lds[OFF_LOG + jd + 16 * i] = pp;
    }
  }
  __syncthreads();

  // ---- em + gumbel + sampled (wave 0 only, lane j) ----
  if (tid < 64) {
    int j = tid;
    float l = lds[OFF_LOG + j] + b2[0];
    float mjv = lds[OFF_MASKR + j];
    float mx = l;
#pragma unroll
    for (int mm = 1; mm < 64; mm <<= 1) mx = fmaxf(mx, __shfl_xor(mx, mm, 64));
    float pv = expf(l - mx);
    float Z = pv;
#pragma unroll
    for (int mm = 1; mm < 64; mm <<= 1) Z += __shfl_xor(Z, mm, 64);
    float ep = (pv / Z) * mjv;
    float S = ep;
#pragma unroll
    for (int mm = 1; mm < 64; mm <<= 1) S += __shfl_xor(S, mm, 64);
    float em = ep / (S + 1e-10f);
    float u = gu[((size_t)bt * 4 + h) * 64 + j];
    float gg = -logf(-logf(u + 1e-10f) + 1e-10f);
    float l2 = logf(em + 1e-10f) + gg;  // TAU = 1
    float mx2 = l2;
#pragma unroll
    for (int mm = 1; mm < 64; mm <<= 1) mx2 = fmaxf(mx2, __shfl_xor(mx2, mm, 64));
    float p2 = expf(l2 - mx2);
    float Z2 = p2;
#pragma unroll
    for (int mm = 1; mm < 64; mm <<= 1) Z2 += __shfl_xor(Z2, mm, 64);
    float smp = p2 / Z2;
    size_t o = ((size_t)bt * 4 + h) * 64 + j;
    out[o] = em;
    out[524288 + o] = smp;
  }
}

extern "C" void kernel_launch(void* const* d_in, const int* in_sizes, int n_in,
                              void* d_out, int out_size, void* d_ws, size_t ws_size,
                              hipStream_t stream) {
  const float* x    = (const float*)d_in[0];
  const float* A    = (const float*)d_in[1];
  const int*   mask = (const int*)d_in[2];
  const float* gu   = (const float*)d_in[3];
  const float* lng  = (const float*)d_in[4];
  const float* lnb  = (const float*)d_in[5];
  const float* leg  = (const float*)d_in[6];
  const float* leb  = (const float*)d_in[7];
  const float* W    = (const float*)d_in[8];
  const float* bias = (const float*)d_in[9];
  const float* w1   = (const float*)d_in[10];
  const float* b1   = (const float*)d_in[11];
  const float* w2   = (const float*)d_in[12];
  const float* b2   = (const float*)d_in[13];
  float* out = (float*)d_out;
  float* ws  = (float*)d_ws;

  float* xn = ws;                    // 131072 floats
  float* T1 = xn + 131072;           // 1572864 floats
  float* T2 = T1 + 1572864;          // 1572864 floats

  k_node_ln<<<512, 256, 0, stream>>>(x, mask, lng, lnb, xn);
  k_t12<<<256, 256, 0, stream>>>(xn, W, bias, T1, T2);
  k_main<<<8192, 256, 0, stream>>>(A, mask, gu, leg, leb, W, w1, b1, w2, b2,
                                   T1, T2, out);
}

// Round 2
// 231.950 us; speedup vs baseline: 5.5880x; 5.5880x over previous
//
#include <hip/hip_runtime.h>
#include <math.h>

// EdgeSelector: B=32, N=64, D=64, H=4, E=256, HD=64
// out = [em (32,64,4,64) | sampled (32,64,4,64)] f32
// ws: xn[2048*64] | T1[2048*768] | T2[2048*768] f32

typedef __attribute__((ext_vector_type(8))) short short8;   // 8 bf16 = 4 VGPR
typedef __attribute__((ext_vector_type(4))) short short4v;  // 4 bf16 = 8 B
typedef __attribute__((ext_vector_type(4))) float f32x4;

__device__ __forceinline__ short f2b(float f) {  // RNE f32->bf16
  unsigned u = __builtin_bit_cast(unsigned, f);
  unsigned r = (u + 0x7FFFu + ((u >> 16) & 1u)) >> 16;
  return (short)r;
}

#define AN_S 136   // row stride (shorts) for 128-wide bf16 tiles (An, Wc)
#define TS   72    // row stride (shorts) for 64-wide bf16 tiles

// LDS byte offsets (total 65,280 B -> 2 blocks/CU)
#define OFF_R0 0        // An [64][136] b16; after proj: w [64][72] @0
#define OFF_W1 9216     //                               w1 [64][72]
#define OFF_R1 18432    // Wc [64][136] b16; after proj: A2 [64][72]
#define OFF_Q  35840    // q  [64][72] b16
#define OFF_K  45056    // k  [64][72] b16
#define OFF_VT 54272    // vT [64][72] b16 (vT[d][k])
#define OFF_F  63488    // f32: T2h[192] | mask[64]@192 | logits[64]@256 | b1[64]@320 | w2[64]@384
#define LDS_BYTES 65280

// ---------------- K1: xn = LN(x)*g+b, zeroed where row has no neighbors ----
__global__ __launch_bounds__(256) void k_node_ln(
    const float* __restrict__ x, const int* __restrict__ mask,
    const float* __restrict__ g, const float* __restrict__ bb,
    float* __restrict__ xn) {
  int tid = threadIdx.x;
  int row = blockIdx.x * 4 + (tid >> 6);
  int lane = tid & 63;
  float v = x[row * 64 + lane];
  float s = v;
#pragma unroll
  for (int m = 1; m < 64; m <<= 1) s += __shfl_xor(s, m, 64);
  float mean = s * (1.0f / 64.0f);
  float dv = v - mean;
  float s2 = dv * dv;
#pragma unroll
  for (int m = 1; m < 64; m <<= 1) s2 += __shfl_xor(s2, m, 64);
  float rstd = rsqrtf(s2 * (1.0f / 64.0f) + 1e-5f);
  float msum = (float)mask[row * 64 + lane];
#pragma unroll
  for (int m = 1; m < 64; m <<= 1) msum += __shfl_xor(msum, m, 64);
  float ped = (msum > 0.0f) ? 1.0f : 0.0f;
  xn[row * 64 + lane] = (dv * rstd * g[lane] + bb[lane]) * ped;
}

// ---------------- K2: T1[r,f]=W[f,0:64]·xn[r]; T2[r,f]=W[f,64:128]·xn[r]+bias[f]
__global__ __launch_bounds__(256) void k_t12(
    const float* __restrict__ xn, const float* __restrict__ W,
    const float* __restrict__ bias, float* __restrict__ T1, float* __restrict__ T2) {
  __shared__ __align__(16) float sx[8 * 64];
  int tid = threadIdx.x;
  int r0 = blockIdx.x * 8;
#pragma unroll
  for (int u = 0; u < 2; ++u) {
    int idx = tid + 256 * u;
    sx[idx] = xn[r0 * 64 + idx];
  }
  __syncthreads();
#pragma unroll
  for (int ff = 0; ff < 3; ++ff) {
    int f = tid + 256 * ff;
    float acc1[8], acc2[8];
#pragma unroll
    for (int r = 0; r < 8; ++r) { acc1[r] = 0.f; acc2[r] = 0.f; }
    for (int e4 = 0; e4 < 64; e4 += 4) {
      float4 wa = *(const float4*)&W[f * 256 + e4];
      float4 wb = *(const float4*)&W[f * 256 + 64 + e4];
#pragma unroll
      for (int r = 0; r < 8; ++r) {
        float4 xv = *(const float4*)&sx[r * 64 + e4];
        acc1[r] += wa.x * xv.x + wa.y * xv.y + wa.z * xv.z + wa.w * xv.w;
        acc2[r] += wb.x * xv.x + wb.y * xv.y + wb.z * xv.z + wb.w * xv.w;
      }
    }
    float bv = bias[f];
#pragma unroll
    for (int r = 0; r < 8; ++r) {
      T1[(r0 + r) * 768 + f] = acc1[r];
      T2[(r0 + r) * 768 + f] = acc2[r] + bv;
    }
  }
}

// ---------------- K3: fused per-(b,t,h): MFMA projection + attention + MLP ----
__global__ __launch_bounds__(256) void k_main(
    const float* __restrict__ A, const int* __restrict__ mask,
    const float* __restrict__ gu, const float* __restrict__ leg,
    const float* __restrict__ leb, const float* __restrict__ W,
    const float* __restrict__ w1g, const float* __restrict__ b1g,
    const float* __restrict__ w2g, const float* __restrict__ b2g,
    const float* __restrict__ T1, const float* __restrict__ T2,
    float* __restrict__ out) {
  __shared__ __align__(16) unsigned char smem[LDS_BYTES];
  short* sAn = (short*)(smem + OFF_R0);
  short* sW  = (short*)(smem + OFF_R0);   // attn weights, after An dead
  short* sW1 = (short*)(smem + OFF_W1);
  short* sWc = (short*)(smem + OFF_R1);
  short* sA2 = (short*)(smem + OFF_R1);   // after Wc dead
  short* sQ  = (short*)(smem + OFF_Q);
  short* sK  = (short*)(smem + OFF_K);
  short* sVT = (short*)(smem + OFF_VT);
  float* sF  = (float*)(smem + OFF_F);

  int tid = threadIdx.x;
  // XCD-aware swizzle: the 4 head-blocks of each (b,t) land on one XCD (8192%8==0)
  int bid0 = blockIdx.x;
  int wg = (bid0 & 7) * 1024 + (bid0 >> 3);
  int h = wg & 3;
  int t = (wg >> 2) & 63;
  int b = wg >> 8;
  int bt = b * 64 + t;

  int wave = tid >> 6, lane = tid & 63;
  int lr = lane & 15, lh = lane >> 4;

  // ---- stage small constants ----
  if (tid < 192)
    sF[tid] = T2[bt * 768 + (tid >> 6) * 256 + h * 64 + (tid & 63)];
  else
    sF[192 + (tid - 192)] = (float)mask[bt * 64 + (tid - 192)];
  if (tid < 64) sF[320 + tid] = b1g[tid];
  else if (tid < 128) sF[384 + (tid - 64)] = w2g[tid - 64];

  // ---- stage An = LN(A[b,m,t,:]) * mask[b,t,m]  (bf16, rows m, cols e<128)
  {
    int half = lane >> 5, l5 = lane & 31;
#pragma unroll
    for (int it = 0; it < 8; ++it) {
      int m = it * 8 + wave * 2 + half;
      const float* Ar = A + ((size_t)((b * 64 + m) * 64 + t)) * 128;
      float4 a = *(const float4*)&Ar[l5 * 4];
      float s = a.x + a.y + a.z + a.w;
      float s2 = a.x * a.x + a.y * a.y + a.z * a.z + a.w * a.w;
#pragma unroll
      for (int mm = 1; mm < 32; mm <<= 1) {
        s += __shfl_xor(s, mm, 64);
        s2 += __shfl_xor(s2, mm, 64);
      }
      float mean = s * (1.0f / 128.0f);
      float var = s2 * (1.0f / 128.0f) - mean * mean;
      float rstd = rsqrtf(var + 1e-5f);
      float mv = (float)mask[bt * 64 + m];
      float4 g4 = *(const float4*)&leg[l5 * 4];
      float4 b4 = *(const float4*)&leb[l5 * 4];
      short4v an;
      an.x = f2b(((a.x - mean) * rstd * g4.x + b4.x) * mv);
      an.y = f2b(((a.y - mean) * rstd * g4.y + b4.y) * mv);
      an.z = f2b(((a.z - mean) * rstd * g4.z + b4.z) * mv);
      an.w = f2b(((a.w - mean) * rstd * g4.w + b4.w) * mv);
      *(short4v*)&sAn[m * AN_S + l5 * 4] = an;
    }
  }
  __syncthreads();

  // ---- projection: qkv[m,d] = An[m,:]·W[Fbase+d,128:256] + T1 + T2h ----
  for (int p = 0; p < 3; ++p) {
    int Fbase = p * 256 + h * 64;
    // stage Wc as [d][e] bf16 (W rows are already e-contiguous)
#pragma unroll
    for (int u = 0; u < 8; ++u) {
      int idx = tid + 256 * u;
      int dR = idx >> 5, c = idx & 31;
      float4 wv = *(const float4*)&W[(size_t)(Fbase + dR) * 256 + 128 + c * 4];
      short4v wb = {f2b(wv.x), f2b(wv.y), f2b(wv.z), f2b(wv.w)};
      *(short4v*)&sWc[dR * AN_S + c * 4] = wb;
    }
    __syncthreads();
    // prefetch T1 (overlaps MFMA)
    float t1v[4][4];
#pragma unroll
    for (int nt = 0; nt < 4; ++nt)
#pragma unroll
      for (int r = 0; r < 4; ++r)
        t1v[nt][r] = T1[(size_t)(b * 64 + wave * 16 + lh * 4 + r) * 768 + Fbase + nt * 16 + lr];
    f32x4 acc[4] = {};
    for (int ks = 0; ks < 4; ++ks) {
      short8 af = *(const short8*)&sAn[(wave * 16 + lr) * AN_S + ks * 32 + lh * 8];
#pragma unroll
      for (int nt = 0; nt < 4; ++nt) {
        short8 bf = *(const short8*)&sWc[(nt * 16 + lr) * AN_S + ks * 32 + lh * 8];
        acc[nt] = __builtin_amdgcn_mfma_f32_16x16x32_bf16(af, bf, acc[nt], 0, 0, 0);
      }
    }
#pragma unroll
    for (int nt = 0; nt < 4; ++nt)
#pragma unroll
      for (int r = 0; r < 4; ++r) {
        int m = wave * 16 + lh * 4 + r;
        int dcol = nt * 16 + lr;
        float val = acc[nt][r] + t1v[nt][r] + sF[p * 64 + dcol];
        if (p == 0)      sQ[m * TS + dcol] = f2b(val * 0.125f);  // * hd^-0.5
        else if (p == 1) sK[m * TS + dcol] = f2b(val);
        else             sVT[dcol * TS + m] = f2b(val);          // transposed
      }
    __syncthreads();
  }

  // ---- stage w1 bf16 [o][d] into R0+9216 (An dead) ----
#pragma unroll
  for (int u = 0; u < 4; ++u) {
    int idx = tid + 256 * u;
    int o = idx >> 4, c = idx & 15;
    float4 wv = *(const float4*)&w1g[o * 64 + c * 4];
    short4v wb = {f2b(wv.x), f2b(wv.y), f2b(wv.z), f2b(wv.w)};
    *(short4v*)&sW1[o * TS + c * 4] = wb;
  }

  // ---- scores + masked-softmax (exact ref algebra) -> w bf16 [j][k] ----
  {
    f32x4 sc[4] = {};
    for (int ks = 0; ks < 2; ++ks) {
      short8 qf = *(const short8*)&sQ[(wave * 16 + lr) * TS + ks * 32 + lh * 8];
#pragma unroll
      for (int nt = 0; nt < 4; ++nt) {
        short8 kf = *(const short8*)&sK[(nt * 16 + lr) * TS + ks * 32 + lh * 8];
        sc[nt] = __builtin_amdgcn_mfma_f32_16x16x32_bf16(qf, kf, sc[nt], 0, 0, 0);
      }
    }
    float mk[4];
#pragma unroll
    for (int nt = 0; nt < 4; ++nt) mk[nt] = sF[192 + nt * 16 + lr];
#pragma unroll
    for (int r = 0; r < 4; ++r) {
      int j = wave * 16 + lh * 4 + r;
      float mj = sF[192 + j];
      float mx = fmaxf(fmaxf(sc[0][r], sc[1][r]), fmaxf(sc[2][r], sc[3][r]));
#pragma unroll
      for (int mm = 1; mm < 16; mm <<= 1) mx = fmaxf(mx, __shfl_xor(mx, mm, 64));
      float pv[4], Zf = 0.f, S = 0.f;
#pragma unroll
      for (int nt = 0; nt < 4; ++nt) {
        pv[nt] = expf(sc[nt][r] - mx);
        Zf += pv[nt];
        S += pv[nt] * mk[nt];
      }
#pragma unroll
      for (int mm = 1; mm < 16; mm <<= 1) {
        Zf += __shfl_xor(Zf, mm, 64);
        S += __shfl_xor(S, mm, 64);
      }
      // w = (p/Z)*m3 renormed == p*mk*mj / (mj*S + 1e-10*Z)
      float inv = mj / (S + 1e-10f * Zf);
#pragma unroll
      for (int nt = 0; nt < 4; ++nt)
        sW[j * TS + nt * 16 + lr] = f2b(pv[nt] * mk[nt] * inv);
    }
  }
  __syncthreads();

  // ---- A2[j,d] = sum_k w[j,k]*v[k,d]  (w as A, vT as B) ----
  {
    f32x4 a2[4] = {};
    for (int ks = 0; ks < 2; ++ks) {
      short8 wf = *(const short8*)&sW[(wave * 16 + lr) * TS + ks * 32 + lh * 8];
#pragma unroll
      for (int nt = 0; nt < 4; ++nt) {
        short8 vf = *(const short8*)&sVT[(nt * 16 + lr) * TS + ks * 32 + lh * 8];
        a2[nt] = __builtin_amdgcn_mfma_f32_16x16x32_bf16(wf, vf, a2[nt], 0, 0, 0);
      }
    }
#pragma unroll
    for (int nt = 0; nt < 4; ++nt)
#pragma unroll
      for (int r = 0; r < 4; ++r)
        sA2[(wave * 16 + lh * 4 + r) * TS + nt * 16 + lr] = f2b(a2[nt][r]);
  }
  __syncthreads();

  // ---- hmid = relu(A2·w1^T + b1); logits[j] = hmid·w2 ----
  {
    f32x4 hm[4] = {};
    for (int ks = 0; ks < 2; ++ks) {
      short8 af = *(const short8*)&sA2[(wave * 16 + lr) * TS + ks * 32 + lh * 8];
#pragma unroll
      for (int nt = 0; nt < 4; ++nt) {
        short8 wf = *(const short8*)&sW1[(nt * 16 + lr) * TS + ks * 32 + lh * 8];
        hm[nt] = __builtin_amdgcn_mfma_f32_16x16x32_bf16(af, wf, hm[nt], 0, 0, 0);
      }
    }
    float b1v[4], w2v[4];
#pragma unroll
    for (int nt = 0; nt < 4; ++nt) {
      b1v[nt] = sF[320 + nt * 16 + lr];
      w2v[nt] = sF[384 + nt * 16 + lr];
    }
#pragma unroll
    for (int r = 0; r < 4; ++r) {
      float pp = 0.f;
#pragma unroll
      for (int nt = 0; nt < 4; ++nt)
        pp += fmaxf(hm[nt][r] + b1v[nt], 0.f) * w2v[nt];
#pragma unroll
      for (int mm = 1; mm < 16; mm <<= 1) pp += __shfl_xor(pp, mm, 64);
      if (lr == 0) sF[256 + wave * 16 + lh * 4 + r] = pp;
    }
  }
  __syncthreads();

  // ---- em + gumbel + sampled (wave 0, lane j) ----
  if (tid < 64) {
    int j = tid;
    float l = sF[256 + j] + b2g[0];
    float mjv = sF[192 + j];
    float mx = l;
#pragma unroll
    for (int mm = 1; mm < 64; mm <<= 1) mx = fmaxf(mx, __shfl_xor(mx, mm, 64));
    float pv = expf(l - mx);
    float Z = pv;
#pragma unroll
    for (int mm = 1; mm < 64; mm <<= 1) Z += __shfl_xor(Z, mm, 64);
    float ep = (pv / Z) * mjv;
    float S = ep;
#pragma unroll
    for (int mm = 1; mm < 64; mm <<= 1) S += __shfl_xor(S, mm, 64);
    float em = ep / (S + 1e-10f);
    float u = gu[((size_t)bt * 4 + h) * 64 + j];
    float gg = -logf(-logf(u + 1e-10f) + 1e-10f);
    float l2 = logf(em + 1e-10f) + gg;  // TAU = 1
    float mx2 = l2;
#pragma unroll
    for (int mm = 1; mm < 64; mm <<= 1) mx2 = fmaxf(mx2, __shfl_xor(mx2, mm, 64));
    float p2 = expf(l2 - mx2);
    float Z2 = p2;
#pragma unroll
    for (int mm = 1; mm < 64; mm <<= 1) Z2 += __shfl_xor(Z2, mm, 64);
    float smp = p2 / Z2;
    size_t o = ((size_t)bt * 4 + h) * 64 + j;
    out[o] = em;
    out[524288 + o] = smp;
  }
}

extern "C" void kernel_launch(void* const* d_in, const int* in_sizes, int n_in,
                              void* d_out, int out_size, void* d_ws, size_t ws_size,
                              hipStream_t stream) {
  const float* x    = (const float*)d_in[0];
  const float* A    = (const float*)d_in[1];
  const int*   mask = (const int*)d_in[2];
  const float* gu   = (const float*)d_in[3];
  const float* lng  = (const float*)d_in[4];
  const float* lnb  = (const float*)d_in[5];
  const float* leg  = (const float*)d_in[6];
  const float* leb  = (const float*)d_in[7];
  const float* W    = (const float*)d_in[8];
  const float* bias = (const float*)d_in[9];
  const float* w1   = (const float*)d_in[10];
  const float* b1   = (const float*)d_in[11];
  const float* w2   = (const float*)d_in[12];
  const float* b2   = (const float*)d_in[13];
  float* out = (float*)d_out;
  float* ws  = (float*)d_ws;

  float* xn = ws;                    // 131072 floats
  float* T1 = xn + 131072;           // 1572864 floats
  float* T2 = T1 + 1572864;          // 1572864 floats

  k_node_ln<<<512, 256, 0, stream>>>(x, mask, lng, lnb, xn);
  k_t12<<<256, 256, 0, stream>>>(xn, W, bias, T1, T2);
  k_main<<<8192, 256, 0, stream>>>(A, mask, gu, leg, leb, W, w1, b1, w2, b2,
                                   T1, T2, out);
}